// Round 14
// baseline (210.266 us; speedup 1.0000x reference)
//
#include <hip/hip_runtime.h>
#include <math.h>

// ---- static config (mirror of reference) ----
#define GNUM 4
#define NG 512
#define NN 2048
#define EE 32768
#define HC 128
#define HEADS 4
#define HID 32
#define GRID_PTS 500
#define QN 20
#define ODIM 32
#define MAXE 160              // per-dst edge cap (deg ~ Poisson(16); P(>159) ~ 0)

#define LOG2E 1.44269504088896340736f
#define NEG_HALF_LOG2E -0.72134752044448170368f
#define N_POW_M02 0.2871745887492588f   // 512^-0.2
#define SIG_K 144.269504089f            // 100 * log2(e)

__device__ __forceinline__ float fexp2(float x){ return __builtin_amdgcn_exp2f(x); }
__device__ __forceinline__ float frcp(float x){ return __builtin_amdgcn_rcpf(x); }

struct SmemKDE {
  __align__(16) float2 xs[NG];   // (x, x^2) 4KB  -- round-9 proven layout
  float4 wred4[8];
  float sc[4];
  float wsum[8], woff[9];
  float redw[QN][8], redg[QN][8];
  float qs[QN];
};
struct SmemXW  { float rows[4][HC]; };
struct SmemGat {
  int   ssrc[4][MAXE];
  float sexp[4][MAXE][HEADS];
  float smax[4][HEADS], sfac[4][HEADS];
};
union Smem { SmemKDE kde; SmemXW xw; SmemGat gat; };

// ================= density stage: 2 blocks per (g,d), half the samples each =================
// db in [0,1024): gd = db>>1, half = db&1. Full 512-sample stats (duplicated, cheap);
// density partial over this block's 256 samples -> gdens[gd*1024 + half*512 + t].
__device__ void dens_phase(Smem& sm, int db, const float* __restrict__ cur, int trans,
        const float* __restrict__ poolw,
        float4* __restrict__ gstats, float* __restrict__ gdens){
  int gd = db >> 1, half = db & 1;
  int g = gd >> 7, d = gd & 127;
  int t = threadIdx.x;
  int lane = t & 63, wave = t >> 6;
  float v = trans ? cur[(size_t)d*NN + g*NG + t]
                  : cur[((size_t)g*NG + t)*HC + d];
  sm.kde.xs[t] = make_float2(v, v*v);
  float mn=v, mx=v, smv=v, sq=v*v;
  #pragma unroll
  for (int m=32; m>0; m>>=1){
    mn = fminf(mn, __shfl_xor(mn, m, 64));
    mx = fmaxf(mx, __shfl_xor(mx, m, 64));
    smv += __shfl_xor(smv, m, 64);
    sq += __shfl_xor(sq, m, 64);
  }
  if (lane==0) sm.kde.wred4[wave] = make_float4(mn,mx,smv,sq);
  __syncthreads();
  if (t==0){
    float4 r = sm.kde.wred4[0];
    #pragma unroll
    for (int i=1;i<8;++i){
      float4 bb = sm.kde.wred4[i];
      r.x = fminf(r.x,bb.x); r.y = fmaxf(r.y,bb.y); r.z += bb.z; r.w += bb.w;
    }
    float mean = r.z * (1.f/NG);
    float var  = fmaxf(r.w*(1.f/NG) - mean*mean, 0.f);
    float sd   = sqrtf(var) + (1e-8f/3.f);
    float h    = 1.06f * sd * N_POW_M02;
    float lo = r.x - 1e-6f, hi = r.y + 1e-6f;
    float stp = (hi-lo)*(1.f/(GRID_PTS-1));
    float kk  = NEG_HALF_LOG2E/(h*h);
    float pooled = poolw[0]*mean + poolw[1]*r.y;
    sm.kde.sc[0] = lo; sm.kde.sc[1] = stp; sm.kde.sc[2] = kk;
    if (half==0) gstats[gd] = make_float4(lo, stp, kk, pooled);
  }
  __syncthreads();
  float lo = sm.kde.sc[0], st = sm.kde.sc[1], kk = sm.kde.sc[2];
  float gv = lo + st*(float)t;
  float acc = 0.f;
  if (t < GRID_PTS){
    float c0 = kk*gv*gv, c1 = -2.f*kk*gv;
    const float4* p4 = (const float4*)sm.kde.xs;
    int i0 = half*128;                   // 256 float4 total; half = 128 (256 samples)
    #pragma unroll 4
    for (int i=i0; i<i0+128; ++i){
      float4 s2 = p4[i];
      acc += fexp2(fmaf(kk, s2.y, fmaf(c1, s2.x, c0)));
      acc += fexp2(fmaf(kk, s2.w, fmaf(c1, s2.z, c0)));
    }
    gdens[gd*1024 + half*512 + t] = acc;
  }
}

// ================= quantile stage: one block per (g,d), reads both density halves =================
__device__ void quant_phase(Smem& sm, int gd,
        const float4* __restrict__ gstats, const float* __restrict__ gdens,
        const float* __restrict__ kW, const float* __restrict__ kb,
        const float* __restrict__ lpW, const float* __restrict__ lpb,
        const float* __restrict__ beta, float* __restrict__ outg){
  int g = gd >> 7, d = gd & 127;
  int t = threadIdx.x;
  int lane = t & 63, wave = t >> 6;
  float4 stq = gstats[gd];
  float lo = stq.x, st = stq.y, pooled = stq.w;
  float acc = 0.f;
  if (t < GRID_PTS)
    acc = gdens[gd*1024 + t] + gdens[gd*1024 + 512 + t];
  float gv = lo + st*(float)t;
  // inclusive scan
  float sv = acc;
  #pragma unroll
  for (int off=1; off<64; off<<=1){
    float n = __shfl_up(sv, off, 64);
    if (lane >= off) sv += n;
  }
  if (lane==63) sm.kde.wsum[wave] = sv;
  __syncthreads();
  if (t==0){
    float r2 = 0.f;
    #pragma unroll
    for (int i=0;i<8;++i){ sm.kde.woff[i]=r2; r2+=sm.kde.wsum[i]; }
    sm.kde.woff[8]=r2;
  }
  if (t < QN*8){ ((float*)sm.kde.redw)[t]=0.f; ((float*)sm.kde.redg)[t]=0.f; }
  __syncthreads();
  float invt = 1.f/fmaxf(sm.kde.woff[8], 1e-8f);
  float c = (sv + sm.kde.woff[wave]) * invt;
  float cw0 = __shfl(c, 0, 64), cw1 = __shfl(c, 63, 64);
  int qlo = max(0, (int)ceilf((cw0 - 0.17f)*(float)(QN-1)));
  int qhi = min(QN-1, (int)floorf((cw1 + 0.17f)*(float)(QN-1)));
  for (int q=qlo; q<=qhi; ++q){
    float w = 0.f;
    if (t < GRID_PTS){
      float dist = fabsf(c - (float)q*(1.f/(QN-1)));
      w = frcp(1.f + fexp2(SIG_K*dist));
    }
    float gw = gv*w;
    #pragma unroll
    for (int m=32;m>0;m>>=1){
      w  += __shfl_xor(w,  m, 64);
      gw += __shfl_xor(gw, m, 64);
    }
    if (lane==0){ sm.kde.redw[q][wave]=w; sm.kde.redg[q][wave]=gw; }
  }
  __syncthreads();
  if (t < QN){
    float sw=0.f, sgw=0.f;
    #pragma unroll
    for (int i=0;i<8;++i){ sw+=sm.kde.redw[t][i]; sgw+=sm.kde.redg[t][i]; }
    sm.kde.qs[t] = sgw / (sw + 1e-8f);
  }
  __syncthreads();
  if (t < ODIM){
    float a = 0.f;
    const float* kwb = kW + (size_t)d*QN*ODIM + t;
    #pragma unroll
    for (int q=0;q<QN;++q) a += sm.kde.qs[q]*kwb[q*ODIM];
    if (d==0) a += kb[t];
    float bb = pooled*lpW[d*ODIM + t];
    if (d==0) bb += lpb[t];
    float s = beta[t]*(a + bb);
    #pragma unroll
    for (int m=16;m>0;m>>=1) s += __shfl_xor(s, m, 32);
    if (t==0) atomicAdd(&outg[g], s*(1.f/3.f));   // fire-and-forget
  }
}

// ---------------- gather core (4 dst/block; returns this thread's channel value) ----------------
__device__ float gather_core(Smem& sm, int d, int sub, int tl,
        const int* __restrict__ csr, const int* __restrict__ pos,
        const float* __restrict__ als, const float* __restrict__ ald,
        const float* __restrict__ xh, const float* __restrict__ bias){
  int deg = min(pos[d], MAXE-1);
  int E = deg + 1;                       // + self loop
  const int* base = csr + d*MAXE;
  float a0 = ald[d*4+0], a1 = ald[d*4+1], a2 = ald[d*4+2], a3 = ald[d*4+3];
  for (int i=tl; i<E; i+=128){
    int s = (i < deg) ? base[i] : d;
    sm.gat.ssrc[sub][i] = s;
    float e0 = als[s*4+0]+a0, e1 = als[s*4+1]+a1, e2 = als[s*4+2]+a2, e3 = als[s*4+3]+a3;
    e0 = (e0>=0.f)? e0 : 0.2f*e0;
    e1 = (e1>=0.f)? e1 : 0.2f*e1;
    e2 = (e2>=0.f)? e2 : 0.2f*e2;
    e3 = (e3>=0.f)? e3 : 0.2f*e3;
    sm.gat.sexp[sub][i][0]=e0; sm.gat.sexp[sub][i][1]=e1;
    sm.gat.sexp[sub][i][2]=e2; sm.gat.sexp[sub][i][3]=e3;
  }
  __syncthreads();
  if (tl < HEADS){
    float m = -INFINITY;
    for (int i=0;i<E;++i) m = fmaxf(m, sm.gat.sexp[sub][i][tl]);
    sm.gat.smax[sub][tl] = m;
  }
  __syncthreads();
  for (int i=tl; i<E; i+=128){
    #pragma unroll
    for (int h=0;h<HEADS;++h)
      sm.gat.sexp[sub][i][h] = fexp2(LOG2E*(sm.gat.sexp[sub][i][h]-sm.gat.smax[sub][h]));
  }
  __syncthreads();
  if (tl < HEADS){
    float sdn = 0.f;
    for (int i=0;i<E;++i) sdn += sm.gat.sexp[sub][i][tl];
    sm.gat.sfac[sub][tl] = 1.f/(sdn + 1e-16f);
  }
  __syncthreads();
  int h = tl >> 5;
  float fac = sm.gat.sfac[sub][h];
  float acc = bias[tl];
  for (int i=0;i<E;++i)
    acc += sm.gat.sexp[sub][i][h]*fac * xh[(size_t)sm.gat.ssrc[sub][i]*HC + tl];
  __syncthreads();                        // gat LDS free for reuse after this
  return acc;
}

// ---------------- xw helper: GEMV row (in LDS rows[sub]) -> xh + logits ----------------
__device__ void xw_emit(Smem& sm, int sub, int j, int n,
        const float* __restrict__ W, const float* __restrict__ as_, const float* __restrict__ ad_,
        float* __restrict__ xh, float* __restrict__ als, float* __restrict__ ald){
  float acc = 0.f;
  #pragma unroll 8
  for (int c2=0;c2<HC;++c2)
    acc += sm.xw.rows[sub][c2]*W[(size_t)c2*HC + j];
  xh[(size_t)n*HC + j] = acc;
  int h = j >> 5, cc = j & 31;
  float ps = acc*as_[h*HID+cc], pd = acc*ad_[h*HID+cc];
  #pragma unroll
  for (int m=16;m>0;m>>=1){
    ps += __shfl_xor(ps, m, 32);
    pd += __shfl_xor(pd, m, 32);
  }
  if (cc==0){ als[n*HEADS+h]=ps; ald[n*HEADS+h]=pd; }
}

// ---------------- transpose write: rows[4][128] -> curT[c][n0..n0+3] as float4 ----------------
__device__ void write_transposed(Smem& sm, int t, int n0, float* __restrict__ curT){
  if (t < HC){
    float4 v = make_float4(sm.xw.rows[0][t], sm.xw.rows[1][t],
                           sm.xw.rows[2][t], sm.xw.rows[3][t]);
    *(float4*)(curT + (size_t)t*NN + n0) = v;
  }
}

// ================= zero: pos[2048] + out[g]=h0 =================
__global__ __launch_bounds__(1024) void k_zero(int* __restrict__ pos,
        float* __restrict__ outg, const float* __restrict__ h0){
  int t = threadIdx.x;
  pos[t] = 0; pos[t+1024] = 0;
  if (t < GNUM) outg[t] = h0[0];
}

// ================= A: dens0(x) x1024 | xw0(x)+CSR fill x512 =================
__global__ __launch_bounds__(512) void k_A(const float* __restrict__ x,
        const float* __restrict__ poolw, float4* __restrict__ gstatsA, float* __restrict__ gdensA,
        const float* __restrict__ W, const float* __restrict__ as_, const float* __restrict__ ad_,
        float* __restrict__ xh, float* __restrict__ als, float* __restrict__ ald,
        const int* __restrict__ src, const int* __restrict__ dst,
        int* __restrict__ pos, int* __restrict__ csr){
  __shared__ Smem sm;
  int t = threadIdx.x;
  if (blockIdx.x < 1024){
    dens_phase(sm, blockIdx.x, x, 0, poolw, gstatsA, gdensA);
  } else {
    int b2 = blockIdx.x - 1024;
    if (t < 64){
      int e = b2*64 + t;
      int dd = dst[e];
      int pp = atomicAdd(&pos[dd], 1);
      if (pp < MAXE) csr[dd*MAXE + pp] = src[e];
    }
    int sub = t >> 7, j = t & 127;
    int n = b2*4 + sub;
    sm.xw.rows[sub][j] = x[(size_t)n*HC + j];
    __syncthreads();
    xw_emit(sm, sub, j, n, W, as_, ad_, xh, als, ald);
  }
}

// ================= B: quant0 x512 | gather0->cur1T + xw1 x512 =================
__global__ __launch_bounds__(512) void k_B(const float4* __restrict__ gstatsA,
        const float* __restrict__ gdensA,
        const float* __restrict__ kW0, const float* __restrict__ kb0,
        const float* __restrict__ lpW0, const float* __restrict__ lpb0,
        const float* __restrict__ beta, float* __restrict__ outg,
        const int* __restrict__ csr, const int* __restrict__ pos,
        const float* __restrict__ als, const float* __restrict__ ald,
        const float* __restrict__ xh, const float* __restrict__ Bi0,
        float* __restrict__ cur1T,
        const float* __restrict__ W1, const float* __restrict__ as1, const float* __restrict__ ad1,
        float* __restrict__ xh2, float* __restrict__ als2, float* __restrict__ ald2){
  __shared__ Smem sm;
  int t = threadIdx.x;
  if (blockIdx.x < 512){
    quant_phase(sm, blockIdx.x, gstatsA, gdensA, kW0, kb0, lpW0, lpb0, beta, outg);
  } else {
    int b2 = blockIdx.x - 512;
    int sub = t >> 7, tl = t & 127;
    int d2 = b2*4 + sub;
    float acc = gather_core(sm, d2, sub, tl, csr, pos, als, ald, xh, Bi0);
    sm.xw.rows[sub][tl] = fmaxf(acc, 0.f);   // post-relu for kde1 + xw1
    __syncthreads();
    write_transposed(sm, t, b2*4, cur1T);
    xw_emit(sm, sub, tl, d2, W1, as1, ad1, xh2, als2, ald2);
  }
}

// ================= C: dens1(cur1T) x1024 | gather1->cur2T x512 =================
__global__ __launch_bounds__(512) void k_C(const float* __restrict__ cur1T,
        const float* __restrict__ poolw, float4* __restrict__ gstatsB, float* __restrict__ gdensB,
        const int* __restrict__ csr, const int* __restrict__ pos,
        const float* __restrict__ als2, const float* __restrict__ ald2,
        const float* __restrict__ xh2, const float* __restrict__ Bi1,
        float* __restrict__ cur2T){
  __shared__ Smem sm;
  int t = threadIdx.x;
  if (blockIdx.x < 1024){
    dens_phase(sm, blockIdx.x, cur1T, 1, poolw, gstatsB, gdensB);
  } else {
    int b2 = blockIdx.x - 1024;
    int sub = t >> 7, tl = t & 127;
    int d2 = b2*4 + sub;
    float acc = gather_core(sm, d2, sub, tl, csr, pos, als2, ald2, xh2, Bi1);
    sm.xw.rows[sub][tl] = acc;               // no relu on last layer
    __syncthreads();
    write_transposed(sm, t, b2*4, cur2T);
  }
}

// ================= D: quant1 x512 | dens2(cur2T) x1024 =================
__global__ __launch_bounds__(512) void k_D(const float4* __restrict__ gstatsB,
        const float* __restrict__ gdensB,
        const float* __restrict__ kW1, const float* __restrict__ kb1,
        const float* __restrict__ lpW1, const float* __restrict__ lpb1,
        const float* __restrict__ beta, float* __restrict__ outg,
        const float* __restrict__ cur2T, const float* __restrict__ poolw,
        float4* __restrict__ gstatsA, float* __restrict__ gdensA){
  __shared__ Smem sm;
  if (blockIdx.x < 512){
    quant_phase(sm, blockIdx.x, gstatsB, gdensB, kW1, kb1, lpW1, lpb1, beta, outg);
  } else {
    dens_phase(sm, blockIdx.x - 512, cur2T, 1, poolw, gstatsA, gdensA);
  }
}

// ================= E: quant2 x512 =================
__global__ __launch_bounds__(512) void k_E(const float4* __restrict__ gstatsA,
        const float* __restrict__ gdensA,
        const float* __restrict__ kW2, const float* __restrict__ kb2,
        const float* __restrict__ lpW2, const float* __restrict__ lpb2,
        const float* __restrict__ beta, float* __restrict__ outg){
  __shared__ Smem sm;
  quant_phase(sm, blockIdx.x, gstatsA, gdensA, kW2, kb2, lpW2, lpb2, beta, outg);
}

extern "C" void kernel_launch(void* const* d_in, const int* in_sizes, int n_in,
                              void* d_out, int out_size, void* d_ws, size_t ws_size,
                              hipStream_t stream) {
  (void)in_sizes; (void)n_in; (void)out_size; (void)ws_size;
  const float* x    = (const float*)d_in[0];
  const int*   ei   = (const int*)d_in[1];
  const int*   srcp = ei;
  const int*   dstp = ei + EE;
  const float* W[2]   = {(const float*)d_in[3], (const float*)d_in[7]};
  const float* As[2]  = {(const float*)d_in[4], (const float*)d_in[8]};
  const float* Ad[2]  = {(const float*)d_in[5], (const float*)d_in[9]};
  const float* Bi[2]  = {(const float*)d_in[6], (const float*)d_in[10]};
  const float* lpW[3] = {(const float*)d_in[11], (const float*)d_in[13], (const float*)d_in[15]};
  const float* lpb[3] = {(const float*)d_in[12], (const float*)d_in[14], (const float*)d_in[16]};
  const float* kW[3]  = {(const float*)d_in[17], (const float*)d_in[19], (const float*)d_in[21]};
  const float* kb[3]  = {(const float*)d_in[18], (const float*)d_in[20], (const float*)d_in[22]};
  const float* poolw  = (const float*)d_in[23];
  const float* beta   = (const float*)d_in[24];
  const float* h0     = (const float*)d_in[25];
  float* out = (float*)d_out;

  // workspace layout (floats unless noted; all offsets 16B-aligned)
  float* ws = (float*)d_ws;
  float* cur1T  = ws;                    // 262144 (transposed [128][2048])
  float* cur2T  = cur1T + 262144;        // 262144
  float* xh     = cur2T + 262144;        // 262144 (layer 0)
  float* xh2    = xh + 262144;           // 262144 (layer 1)
  float* als    = xh2 + 262144;          // 8192
  float* ald    = als + 8192;            // 8192
  float* als2   = ald + 8192;            // 8192
  float* ald2   = als2 + 8192;           // 8192
  float* gdensA = ald2 + 8192;           // 512*1024 = 524288
  float* gdensB = gdensA + 524288;       // 524288
  float4* gstatsA = (float4*)(gdensB + 524288);  // 512 float4
  float4* gstatsB = gstatsA + 512;               // 512 float4
  int*   pos    = (int*)(gstatsB + 512); // 2048
  int*   csr    = pos + 2048;            // 2048*160

  k_zero<<<1, 1024, 0, stream>>>(pos, out, h0);
  k_A<<<1536, 512, 0, stream>>>(x, poolw, gstatsA, gdensA,
                                W[0], As[0], Ad[0], xh, als, ald,
                                srcp, dstp, pos, csr);
  k_B<<<1024, 512, 0, stream>>>(gstatsA, gdensA, kW[0], kb[0], lpW[0], lpb[0], beta, out,
                                csr, pos, als, ald, xh, Bi[0], cur1T,
                                W[1], As[1], Ad[1], xh2, als2, ald2);
  k_C<<<1536, 512, 0, stream>>>(cur1T, poolw, gstatsB, gdensB,
                                csr, pos, als2, ald2, xh2, Bi[1], cur2T);
  k_D<<<1536, 512, 0, stream>>>(gstatsB, gdensB, kW[1], kb[1], lpW[1], lpb[1], beta, out,
                                cur2T, poolw, gstatsA, gdensA);
  k_E<<<512, 512, 0, stream>>>(gstatsA, gdensA, kW[2], kb[2], lpW[2], lpb[2], beta, out);
}